// Round 9
// baseline (229.910 us; speedup 1.0000x reference)
//
#include <hip/hip_runtime.h>

typedef __attribute__((ext_vector_type(8))) short short8;
typedef __attribute__((ext_vector_type(8))) __bf16 bf16x8;
typedef __attribute__((ext_vector_type(4))) float f32x4;
typedef __attribute__((ext_vector_type(4))) unsigned short ushort4_t;
typedef __attribute__((ext_vector_type(4))) unsigned int uint4_t;
typedef __attribute__((ext_vector_type(2))) unsigned int uint2_t;

#define NB   4096
#define NIN  4096
#define NX   4098
#define NC   128
#define NO   64
#define NA   64
#define NOUT 1024
#define NSLOT (NC * NA)          // 8192 slots
#define NROW  (NC * NO)          // 8192 buffer rows
#define BT    512                // b-tile width
#define NBT   (NB / BT)          // 8 b-tiles
#define FCAP  32
#define RCAP  32

__device__ __forceinline__ unsigned short f2bf(float f) {
  unsigned b = __builtin_bit_cast(unsigned, f);
  b += 0x7FFFu + ((b >> 16) & 1u);
  return (unsigned short)(b >> 16);
}
__device__ __forceinline__ float bf2f(unsigned short u) {
  return __builtin_bit_cast(float, (unsigned)u << 16);
}
// f32 -> e4m3fn: RNE, FTZ below 2^-6, clamp 448.  (R4-verified)
__device__ __forceinline__ unsigned f2e4m3(float f) {
  unsigned u = __builtin_bit_cast(unsigned, f);
  unsigned s = (u >> 24) & 0x80u;
  unsigned mag = u & 0x7fffffffu;
  mag = mag > 0x43E00000u ? 0x43E00000u : mag;
  unsigned r = mag + 0x7FFFFu + ((mag >> 20) & 1u);
  int e = (int)(r >> 23) - 120;
  unsigned v = (e <= 0) ? 0u : (((unsigned)e << 3) | ((r >> 20) & 7u));
  return v | s;
}
__device__ __forceinline__ unsigned e4m32bf(unsigned f) {
  unsigned t = (((f & 0x7Fu) << 4) + 0x3C00u) | ((f & 0x80u) << 8);
  return (f & 0x78u) ? t : 0u;
}
__device__ __forceinline__ uint4_t dec8(uint2_t d) {
  uint4_t o;
#pragma unroll
  for (int k = 0; k < 4; ++k) {
    unsigned src = (k < 2) ? d[0] : d[1];
    unsigned sh = (k & 1) * 16;
    unsigned b0 = (src >> sh) & 0xFFu;
    unsigned b1 = (src >> (sh + 8)) & 0xFFu;
    o[k] = e4m32bf(b0) | (e4m32bf(b1) << 16);
  }
  return o;
}

// ---------------------------------------------------------------------------
// plan_zero / plan_build: CSR plans from axon/out_idx.
//  featslots[f][..]: static slots sourced from pool row f (f < NX)
//  rowslots[r][..]:  dynamic slots consuming buffer row r
//  omask[r]: final gather needs row r
// List order from atomics is nondeterministic but targets/values are sets ->
// output deterministic.
// ---------------------------------------------------------------------------
__global__ __launch_bounds__(1024) void plan_zero(
    int* __restrict__ featcnt, int* __restrict__ rowcnt,
    unsigned char* __restrict__ omask) {
  int t = threadIdx.x;
  for (int i = t; i < NX; i += 1024) featcnt[i] = 0;
  for (int i = t; i < NROW; i += 1024) { rowcnt[i] = 0; omask[i] = 0; }
}

__global__ __launch_bounds__(1024) void plan_build(
    const int* __restrict__ axon, const int* __restrict__ oidx,
    int* __restrict__ featcnt, int* __restrict__ featslots,
    int* __restrict__ rowcnt, int* __restrict__ rowslots,
    unsigned char* __restrict__ omask) {
  int bid = blockIdx.x, t = threadIdx.x;
  if (bid < 8) {
    int s = bid * 1024 + t;
    int idx = axon[s];
    if (idx < NX) {
      int k = atomicAdd(&featcnt[idx], 1);
      if (k < FCAP) featslots[idx * FCAP + k] = s;
    } else {
      int r = idx - NX;
      int k = atomicAdd(&rowcnt[r], 1);
      if (k < RCAP) rowslots[r * RCAP + k] = s;
    }
  } else if (t < NOUT) {
    int idx = oidx[t];
    if (idx >= NX) omask[idx - NX] = 1;
  }
}

// ---------------------------------------------------------------------------
// prep: bid<4096: transpose a 64b x 64f tile of x and write fp8 into every
// static slot sourced by those features (GA[bt][slot][512]).
// bid>=4096: W f32 -> bf16.
// ---------------------------------------------------------------------------
__global__ __launch_bounds__(256) void prep_kernel(
    const float* __restrict__ x, const float* __restrict__ W,
    unsigned char* __restrict__ GA, unsigned short* __restrict__ Wb,
    const int* __restrict__ featcnt, const int* __restrict__ featslots) {
  int bid = blockIdx.x, t = threadIdx.x;
  if (bid < 4096) {
    __shared__ unsigned short tile[64][68];   // [b_local][f_local]
    int b0 = (bid >> 6) << 6, n0 = (bid & 63) << 6;
    int r = t >> 4, c4 = (t & 15) << 2;
#pragma unroll
    for (int rr = 0; rr < 4; ++rr) {
      int row = r + rr * 16;
      float4 v = *(const float4*)(x + (size_t)(b0 + row) * NIN + n0 + c4);
      tile[row][c4 + 0] = f2bf(v.x);
      tile[row][c4 + 1] = f2bf(v.y);
      tile[row][c4 + 2] = f2bf(v.z);
      tile[row][c4 + 3] = f2bf(v.w);
    }
    __syncthreads();
    int w = t >> 6, lane = t & 63;
    int bt = b0 >> 9, bl0 = b0 & 511;
    unsigned char pv = (unsigned char)f2e4m3(bf2f(0));  // dummy init
    for (int fl = 0; fl < 64; ++fl) {
      int f = n0 + fl;
      int cnt = featcnt[f];
      if (cnt > FCAP) cnt = FCAP;
      if (cnt == 0) continue;
      pv = (unsigned char)f2e4m3(bf2f(tile[lane][fl]));
      for (int si = w; si < cnt; si += 4) {
        int s = featslots[f * FCAP + si];
        GA[((size_t)bt * NSLOT + s) * BT + bl0 + lane] = pv;
      }
    }
  } else {
    size_t i0 = (size_t)(bid - 4096) * 2048 + (size_t)t * 8;
    float4 v0 = *(const float4*)(W + i0);
    float4 v1 = *(const float4*)(W + i0 + 4);
    ushort4_t a, b;
    a.x = f2bf(v0.x); a.y = f2bf(v0.y); a.z = f2bf(v0.z); a.w = f2bf(v0.w);
    b.x = f2bf(v1.x); b.y = f2bf(v1.y); b.z = f2bf(v1.z); b.w = f2bf(v1.w);
    *(ushort4_t*)(Wb + i0) = a;
    *(ushort4_t*)(Wb + i0 + 4) = b;
  }
}

// const rows: slots sourced from pool rows 4096 (zero) / 4097 (one).
__global__ __launch_bounds__(256) void const_fill(
    unsigned char* __restrict__ GA,
    const int* __restrict__ featcnt, const int* __restrict__ featslots) {
  int t = threadIdx.x;
#pragma unroll
  for (int fi = 0; fi < 2; ++fi) {
    int f = NIN + fi;
    unsigned val = fi ? 0x38383838u : 0u;   // fp8 1.0 = 0x38
    int cnt = featcnt[f];
    if (cnt > FCAP) cnt = FCAP;
    for (int si = 0; si < cnt; ++si) {
      int s = featslots[f * FCAP + si];
      for (int bt = 0; bt < NBT; ++bt)
        if (t < 128)
          *(unsigned*)(GA + ((size_t)bt * NSLOT + s) * BT + t * 4) = val;
    }
  }
}

// ---------------------------------------------------------------------------
// cycle v9: slot-ordered operand streaming.
// Grid (8, 128), 512 thr = 8 waves. Block (bt, c) reads its 64 slots
// (32 KB contiguous window): static slots from GA, dynamic from GDsrc
// (zeros when first). dec8 -> reg 8x8 transpose -> swizzled LDS [b][a]
// (addr_u16(b,a) = b*64 + ((a>>3)^(b&7)^((b>>5)&7))*8 + (a&7)) -> MFMA.
// Epilogue MODE 0: pack fp8 rows in LDS, scatter each row to its consumer
// slots in GDdst via rowslots CSR (512 B per slot per block).
// Epilogue MODE 1: bf16 rows -> bufD canonical [row][b], omask rows only.
// ---------------------------------------------------------------------------
template <int MODE>
__global__ __launch_bounds__(512) void cycle_kernel(
    const unsigned char* __restrict__ GA, const unsigned char* __restrict__ GDsrc,
    unsigned char* __restrict__ GDdst, unsigned short* __restrict__ bufD,
    const unsigned short* __restrict__ Wb, const int* __restrict__ axon,
    const int* __restrict__ rowcnt, const int* __restrict__ rowslots,
    const unsigned char* __restrict__ omask, int first) {
  __shared__ __align__(16) unsigned short SM[64 * 520];  // 66.6 KiB
  int bt = blockIdx.x, c = blockIdx.y;
  int t = threadIdx.x;
  int lane = t & 63, w = t >> 6;
  int ln = lane & 15, g = lane >> 4;
  const int* arow = axon + (c << 6);

  // ---- stage: wave w owns slots a = w*8 .. w*8+7 ----
  {
    uint4_t rbf[8];
#pragma unroll
    for (int r = 0; r < 8; ++r) {
      int a = w * 8 + r;
      int s = (c << 6) + a;
      int idx = arow[a];
      const unsigned char* base = nullptr;
      if (idx < NX)    base = GA;
      else if (!first) base = GDsrc;
      if (base) {
        uint2_t d = *(const uint2_t*)(base + ((size_t)bt * NSLOT + s) * BT + lane * 8);
        rbf[r] = dec8(d);
      } else {
        rbf[r] = (uint4_t)(0u);
      }
    }
    unsigned lo[4][4], hi[4][4];
#pragma unroll
    for (int p = 0; p < 4; ++p)
#pragma unroll
      for (int k = 0; k < 4; ++k) {
        unsigned wi = rbf[2 * p][k], wj = rbf[2 * p + 1][k];
        lo[p][k] = __builtin_amdgcn_perm(wj, wi, 0x05040100u);
        hi[p][k] = __builtin_amdgcn_perm(wj, wi, 0x07060302u);
      }
#pragma unroll
    for (int e = 0; e < 8; ++e) {
      int k = e >> 1;
      uint4_t col;
      if (e & 1) { col[0] = hi[0][k]; col[1] = hi[1][k]; col[2] = hi[2][k]; col[3] = hi[3][k]; }
      else       { col[0] = lo[0][k]; col[1] = lo[1][k]; col[2] = lo[2][k]; col[3] = lo[3][k]; }
      int b = lane * 8 + e;
      int sw = w ^ (b & 7) ^ ((b >> 5) & 7);
      *(uint4_t*)&SM[b * 64 + (sw << 3)] = col;
    }
  }
  __syncthreads();

  // ---- compute: wave w covers b-local [w*64, w*64+64) ----
  const unsigned short* wrow = Wb + ((size_t)c << 12);
  bool grp[4];
#pragma unroll
  for (int j = 0; j < 4; ++j) {
    if (MODE == 1) grp[j] = __any((int)(omask[(c << 6) + j * 16 + ln] != 0));
    else           grp[j] = __any((int)(rowcnt[(c << 6) + j * 16 + ln] > 0));
  }

  f32x4 acc[4][4];
#pragma unroll
  for (int i = 0; i < 4; ++i)
#pragma unroll
    for (int j = 0; j < 4; ++j) acc[i][j] = (f32x4)(0.f);

#pragma unroll
  for (int ks = 0; ks < 2; ++ks) {
    short8 ag[4];
#pragma unroll
    for (int i = 0; i < 4; ++i) {
      int bl = (w << 6) + (i << 4) + ln;
      int c8 = (ks << 2) + g;
      int sw = c8 ^ (bl & 7) ^ ((bl >> 5) & 7);
      ag[i] = *(const short8*)&SM[bl * 64 + (sw << 3)];
    }
#pragma unroll
    for (int j = 0; j < 4; ++j) {
      if (!grp[j]) continue;
      short8 bw = *(const short8*)(wrow + ((size_t)(j * 16 + ln) << 6) + ks * 32 + g * 8);
#pragma unroll
      for (int i = 0; i < 4; ++i)
        acc[i][j] = __builtin_amdgcn_mfma_f32_16x16x32_bf16(
            __builtin_bit_cast(bf16x8, ag[i]), __builtin_bit_cast(bf16x8, bw),
            acc[i][j], 0, 0, 0);
    }
  }

  // ---- epilogue ----
  __syncthreads();  // all MFMA reads of G done; reuse SM
  if (MODE == 0) {
    unsigned char* SM8 = (unsigned char*)SM;
    // frag(i,j): lane holds o=j*16+ln, b-local = w*64+i*16+g*4+{0..3}
#pragma unroll
    for (int j = 0; j < 4; ++j) {
      int o = j * 16 + ln;
#pragma unroll
      for (int i = 0; i < 4; ++i) {
        unsigned pk = 0;
#pragma unroll
        for (int r = 0; r < 4; ++r)
          pk |= f2e4m3(fmaxf(acc[i][j][r], 0.f)) << (r * 8);
        *(unsigned*)&SM8[o * 528 + (w << 6) + (i << 4) + (g << 2)] = pk;
      }
    }
    __syncthreads();
    // wave w scatters rows {it*8+w} to consumer slots (512 B per slot)
#pragma unroll
    for (int it = 0; it < 8; ++it) {
      int row = it * 8 + w;
      int r = (c << 6) + row;
      int cnt = rowcnt[r];
      if (cnt > RCAP) cnt = RCAP;
      if (cnt == 0) continue;
      uint2_t v = *(const uint2_t*)&SM8[row * 528 + lane * 8];
      for (int si = 0; si < cnt; ++si) {
        int slot = rowslots[r * RCAP + si];
        *(uint2_t*)(GDdst + ((size_t)bt * NSLOT + slot) * BT + lane * 8) = v;
      }
    }
  } else {
    // bf16 rows -> bufD canonical, omask rows only
#pragma unroll
    for (int j = 0; j < 4; ++j) {
      int o = j * 16 + ln;
#pragma unroll
      for (int i = 0; i < 4; ++i) {
        ushort4_t pk;
#pragma unroll
        for (int r = 0; r < 4; ++r) pk[r] = f2bf(fmaxf(acc[i][j][r], 0.f));
        *(ushort4_t*)&SM[o * 520 + (w << 6) + (i << 4) + (g << 2)] = pk;
      }
    }
    __syncthreads();
#pragma unroll
    for (int it = 0; it < 8; ++it) {
      int row = it * 8 + w;
      int r = (c << 6) + row;
      if (omask[r] == 0) continue;
      uint4_t v = *(const uint4_t*)&SM[row * 520 + (lane << 3)];
      *(uint4_t*)(bufD + (size_t)r * NB + (bt << 9) + (lane << 3)) = v;
    }
  }
}

// ---------------------------------------------------------------------------
// final: out[b][j]: dynamic j from bufD (bf16, LDS transpose); static j
// straight from x (f32, exact). Grid (16 j-tiles, 16 b-tiles), 256 thr.
// ---------------------------------------------------------------------------
__global__ __launch_bounds__(256) void final_kernel(
    const float* __restrict__ x, const unsigned short* __restrict__ bufD,
    const int* __restrict__ out_idx, float* __restrict__ out) {
  __shared__ unsigned short tile[256][66];
  int j0 = blockIdx.x << 6, b0 = blockIdx.y << 8;
  int t = threadIdx.x;
  {
    int jl = t >> 2, bq = t & 3;
    int idx = out_idx[j0 + jl];
    if (idx >= NX) {
      const unsigned short* src = bufD + (size_t)(idx - NX) * NB;
      int jcol = jl ^ (bq << 4);
#pragma unroll
      for (int k = 0; k < 8; ++k) {
        short8 v = *(const short8*)(src + b0 + bq * 64 + k * 8);
#pragma unroll
        for (int m = 0; m < 8; ++m)
          tile[bq * 64 + k * 8 + m][jcol] = (unsigned short)v[m];
      }
    }
  }
  __syncthreads();
  {
    int j = t & 63, ws = t >> 6;
    int idx = out_idx[j0 + j];
    bool dyn = idx >= NX;
    float cv = (idx == NIN + 1) ? 1.f : 0.f;
    bool isx = idx < NIN;
#pragma unroll
    for (int bb = 0; bb < 64; ++bb) {
      int b = bb * 4 + ws;
      float val;
      if (dyn) {
        int jc = j ^ ((b >> 6) << 4);
        val = bf2f(tile[b][jc]);
      } else if (isx) {
        val = x[(size_t)(b0 + b) * NIN + idx];
      } else {
        val = cv;
      }
      out[(size_t)(b0 + b) * NOUT + j0 + j] = val;
    }
  }
}

// ---------------------------------------------------------------------------
extern "C" void kernel_launch(void* const* d_in, const int* in_sizes, int n_in,
                              void* d_out, int out_size, void* d_ws, size_t ws_size,
                              hipStream_t stream) {
  const float* x    = (const float*)d_in[0];
  const float* W    = (const float*)d_in[1];
  const int*   axon = (const int*)d_in[2];
  const int*   oidx = (const int*)d_in[3];
  float* out = (float*)d_out;

  const size_t G_B    = (size_t)NBT * NSLOT * BT;   // 33,554,432 (fp8)
  const size_t BUFD_B = (size_t)NROW * NB * 2;      // 67,108,864 (bf16)
  const size_t WB_B   = (size_t)NC * NO * NA * 2;   //  1,048,576
  const size_t FC_B   = 32 * 1024;                  // featcnt (NX ints)
  const size_t FS_B   = (size_t)NX * FCAP * 4;      // 524,544 -> pad 576K
  const size_t FS_PAD = 576 * 1024;
  const size_t RC_B   = 64 * 1024;                  // rowcnt
  const size_t RS_B   = (size_t)NROW * RCAP * 4;    // 1 MiB
  const size_t OM_B   = 32 * 1024;                  // omask
  size_t need = 2 * G_B + BUFD_B + WB_B + FC_B + FS_PAD + RC_B + RS_B + OM_B;
  if (ws_size < need) return;  // ~136.5 MB

  char* p = (char*)d_ws;
  unsigned char*  GAb   = (unsigned char*)p;            p += G_B;
  unsigned char*  GBb   = (unsigned char*)p;            p += G_B;
  unsigned short* bufD  = (unsigned short*)p;           p += BUFD_B;
  unsigned short* Wb    = (unsigned short*)p;           p += WB_B;
  int*            featcnt  = (int*)p;                   p += FC_B;
  int*            featslots= (int*)p;                   p += FS_PAD;
  int*            rowcnt   = (int*)p;                   p += RC_B;
  int*            rowslots = (int*)p;                   p += RS_B;
  unsigned char*  omask    = (unsigned char*)p;

  plan_zero<<<1, 1024, 0, stream>>>(featcnt, rowcnt, omask);
  plan_build<<<9, 1024, 0, stream>>>(axon, oidx, featcnt, featslots,
                                     rowcnt, rowslots, omask);
  prep_kernel<<<4352, 256, 0, stream>>>(x, W, GAb, Wb, featcnt, featslots);
  const_fill<<<1, 256, 0, stream>>>(GAb, featcnt, featslots);

  dim3 cg(NBT, NC);
  // c0: reads GA-static (+zeros), writes GB-dyn
  cycle_kernel<0><<<cg, 512, 0, stream>>>(GAb, GBb, GBb, bufD, Wb, axon,
                                          rowcnt, rowslots, omask, 1);
  // c1: reads GA-static + GB-dyn, writes GA-dyn
  cycle_kernel<0><<<cg, 512, 0, stream>>>(GAb, GBb, GAb, bufD, Wb, axon,
                                          rowcnt, rowslots, omask, 0);
  // c2: reads GA-static + GA-dyn, writes GB-dyn
  cycle_kernel<0><<<cg, 512, 0, stream>>>(GAb, GAb, GBb, bufD, Wb, axon,
                                          rowcnt, rowslots, omask, 0);
  // c3: reads GA-static + GB-dyn, writes bufD (omask rows, bf16)
  cycle_kernel<1><<<cg, 512, 0, stream>>>(GAb, GBb, GBb, bufD, Wb, axon,
                                          rowcnt, rowslots, omask, 0);
  final_kernel<<<dim3(NOUT / 64, NB / 256), 256, 0, stream>>>(x, bufD, oidx, out);
}